// Round 7
// baseline (78.508 us; speedup 1.0000x reference)
//
#include <hip/hip_runtime.h>

typedef unsigned short ushort_t;
typedef __attribute__((ext_vector_type(8))) short bf16x8;
typedef __attribute__((ext_vector_type(8))) unsigned short ushort8;
typedef __attribute__((ext_vector_type(4))) float f32x4;

__device__ __forceinline__ unsigned short f2bf(float f) {
  union { float f; unsigned u; } x; x.f = f;
  unsigned r = x.u + 0x7FFFu + ((x.u >> 16) & 1u);   // round-to-nearest-even
  return (unsigned short)(r >> 16);
}

// ---------------- chain part 1: g[b][q][y][c][z] = sum_r f1[b,q,r,y]*lf[c,r,z]
__global__ void chain_g_kernel(const float* __restrict__ f1,
                               const float* __restrict__ lf,
                               float* __restrict__ g) {
  int idx = blockIdx.x * 256 + threadIdx.x;           // 32768 total
  int z = idx & 7, c = (idx >> 3) & 3, y = (idx >> 5) & 7,
      q = (idx >> 8) & 15, b = idx >> 12;
  float s = 0.f;
  #pragma unroll
  for (int r = 0; r < 16; ++r)
    s += f1[((b * 16 + q) * 16 + r) * 8 + y] * lf[(c * 16 + r) * 8 + z];
  g[idx] = s;
}

// ---------------- chain part 2: chainT[o][k] = sum_q f0[a,p,q,x]*g[b,q,y,c,z]
// o = (x*8+y)*8+z ; k = ((a*8+b)*4+c)*4+p
__global__ void chain_kernel(const float* __restrict__ f0,
                             const float* __restrict__ g,
                             ushort_t* __restrict__ chainT) {
  int idx = blockIdx.x * 256 + threadIdx.x;           // 524288 total = o*1024+k
  int k = idx & 1023, o = idx >> 10;
  int p = k & 3, c = (k >> 2) & 3, b = (k >> 4) & 7, a = k >> 7;
  int z = o & 7, y = (o >> 3) & 7, x = o >> 6;
  float s = 0.f;
  #pragma unroll
  for (int q = 0; q < 16; ++q)
    s += f0[((a * 4 + p) * 16 + q) * 8 + x] *
         g[(((b * 16 + q) * 8 + y) * 4 + c) * 8 + z];
  chainT[idx] = f2bf(s);
}

// ---------------- depthwise 3x3 conv -> t[m][k] bf16 (K-contiguous)
// block = (n, h-quad, channel-quarter). grid = 32*8*4 = 1024 blocks.
__global__ __launch_bounds__(256) void conv_kernel(const float* __restrict__ in,
                                                   const float* __restrict__ sf,
                                                   ushort_t* __restrict__ t) {
  __shared__ float in_lds[64][244];
  __shared__ float sf_l[36];
  int bid = blockIdx.x;
  int cq = bid & 3, h4 = (bid >> 2) & 7, n = bid >> 5;
  int h0 = h4 * 4;
  int tid = threadIdx.x;
  if (tid < 36) sf_l[tid] = sf[tid];
  for (int e = tid; e < 384; e += 256) {
    int ch = e / 6, r = e % 6;
    in_lds[ch][r * 40 + 3] = 0.f;
    in_lds[ch][r * 40 + 36] = 0.f;
  }
  const float* inb = in + ((size_t)n * 256 + cq * 64) * 1024;
  #pragma unroll
  for (int i = 0; i < 12; ++i) {
    int e = tid + i * 256;
    int ch = e / 48, rem = e % 48;
    int r = rem >> 3, w4 = rem & 7;
    int hh = h0 - 1 + r;
    float4 v = make_float4(0.f, 0.f, 0.f, 0.f);
    if (hh >= 0 && hh < 32)
      v = *(const float4*)&inb[(size_t)ch * 1024 + hh * 32 + w4 * 4];
    *(float4*)&in_lds[ch][r * 40 + 4 + w4 * 4] = v;
  }
  __syncthreads();
  float sfr[36];
  #pragma unroll
  for (int i = 0; i < 36; ++i) sfr[i] = sf_l[i];
  int w = tid >> 3, gg = tid & 7;
  size_t m0 = (size_t)n * 1024 + (size_t)h0 * 32 + w;
  #pragma unroll
  for (int j = 0; j < 4; ++j) {
    float acc[4][2][4];
    #pragma unroll
    for (int b = 0; b < 2; ++b) {
      int ch = j * 16 + gg * 2 + b;
      float vals[6][3];
      #pragma unroll
      for (int r = 0; r < 6; ++r)
        #pragma unroll
        for (int dw = 0; dw < 3; ++dw)
          vals[r][dw] = in_lds[ch][r * 40 + 3 + w + dw];
      #pragma unroll
      for (int hh = 0; hh < 4; ++hh)
        #pragma unroll
        for (int p = 0; p < 4; ++p) {
          float s = 0.f;
          #pragma unroll
          for (int dr = 0; dr < 3; ++dr)
            #pragma unroll
            for (int dw = 0; dw < 3; ++dw)
              s += vals[hh + dr][dw] * sfr[p * 9 + dr * 3 + dw];
          acc[hh][b][p] = s;
        }
    }
    #pragma unroll
    for (int hh = 0; hh < 4; ++hh) {
      ushort8 outv;
      #pragma unroll
      for (int b = 0; b < 2; ++b)
        #pragma unroll
        for (int p = 0; p < 4; ++p) outv[b * 4 + p] = f2bf(acc[hh][b][p]);
      *(ushort8*)&t[(m0 + hh * 32) * 1024 + (size_t)(cq * 256 + j * 64 + gg * 8)] = outv;
    }
  }
}

// ---------------- GEMM: out[m][o] = sum_k t[m][k]*chainT[o][k] + bias[o]
// 128x128 tile, BK=64, 8 waves (4Mx2N, per-wave 32x64), 64KB LDS -> 2 blocks/CU.
// 8-phase, counted vmcnt, XOR-swizzled LDS, raw s_barrier, setprio.
// SYNC RULES:
//  (RAW) VMCNT(N) goes BEFORE the barrier that releases readers of the staged
//        region (vmcnt is per-wave; readers consume OTHER waves' DMA).
//  (WAR) a STAGE targeting region R issues only after the closing barrier of
//        the phase with the last ds_read of R's old data; those reads are
//        forced serviced pre-barrier via LGKMCNT0 after the mid-barrier.
#define AS1 __attribute__((address_space(1)))
#define AS3 __attribute__((address_space(3)))
#define BARRIER  __builtin_amdgcn_s_barrier()
#define LGKMCNT0 asm volatile("s_waitcnt lgkmcnt(0)" ::: "memory")
#define VMCNT2   asm volatile("s_waitcnt vmcnt(2)" ::: "memory")
#define VMCNT0   asm volatile("s_waitcnt vmcnt(0)" ::: "memory")

__global__ __launch_bounds__(512, 4) void gemm_kernel(const ushort_t* __restrict__ tA,
                                                      const ushort_t* __restrict__ tB,
                                                      const float* __restrict__ bias,
                                                      float* __restrict__ out) {
  __shared__ __align__(16) ushort_t smem[32768];   // 64 KB: As[2][8192] | Bs[2][8192]
  int tid = threadIdx.x;
  int bid = blockIdx.x;                            // 1024 blocks
  int wg = (bid & 7) * 128 + (bid >> 3);           // XCD swizzle (1024%8==0, bijective)
  int tile_m = (wg >> 2) * 128;
  int tile_n = (wg & 3) * 128;

  int lane = tid & 63, wv = tid >> 6;
  int wm = (wv >> 1) * 32, wn = (wv & 1) * 64;
  int lr = lane & 15, kg = lane >> 4;
  int kph0 = ((kg * 8) ^ ((lane & 7) * 8));
  int kph1 = ((32 + kg * 8) ^ ((lane & 7) * 8));
  int arow = wm + lr;
  int brow = wn + lr;

  int srow = tid >> 3;                             // 0..63 within a 64-row set
  int scol = ((tid & 7) ^ (srow & 7)) * 8;
  const ushort_t* sA = tA + (size_t)(tile_m + srow) * 1024 + scol;
  const ushort_t* sB = tB + (size_t)(tile_n + srow) * 1024 + scol;

#define STAGE_A(buf, koff, h)                                                                  \
  __builtin_amdgcn_global_load_lds((const AS1 void*)(sA + (size_t)((h)*64) * 1024 + (koff)),   \
      (AS3 void*)&smem[(buf)*8192 + (h)*4096 + tid*8], 16, 0, 0);
#define STAGE_B(buf, koff, h)                                                                  \
  __builtin_amdgcn_global_load_lds((const AS1 void*)(sB + (size_t)((h)*64) * 1024 + (koff)),   \
      (AS3 void*)&smem[16384 + (buf)*8192 + (h)*4096 + tid*8], 16, 0, 0);

#define READ_A1(dst, buf)                                                                      \
  dst[0] = *(const bf16x8*)&smem[(buf)*8192 + (arow)*64 + kph0];                               \
  dst[1] = *(const bf16x8*)&smem[(buf)*8192 + (arow)*64 + kph1];
#define READ_A2(dst, buf)                                                                      \
  dst[0] = *(const bf16x8*)&smem[(buf)*8192 + (arow + 16)*64 + kph0];                          \
  dst[1] = *(const bf16x8*)&smem[(buf)*8192 + (arow + 16)*64 + kph1];
#define READ_B(dst, nbase, buf)                                                                \
  _Pragma("unroll")                                                                            \
  for (int nf = 0; nf < 2; ++nf) {                                                             \
    dst[nf][0] = *(const bf16x8*)&smem[16384 + (buf)*8192 + (brow + (nbase) + nf*16)*64 + kph0];\
    dst[nf][1] = *(const bf16x8*)&smem[16384 + (buf)*8192 + (brow + (nbase) + nf*16)*64 + kph1];\
  }
#define Q_MFMA(AF, BF, MB, NB)                                                                 \
  __builtin_amdgcn_s_setprio(1);                                                              \
  _Pragma("unroll")                                                                            \
  for (int nf = 0; nf < 2; ++nf)                                                               \
    _Pragma("unroll")                                                                          \
    for (int ks = 0; ks < 2; ++ks)                                                             \
      acc[MB][(NB) + nf] = __builtin_amdgcn_mfma_f32_16x16x32_bf16(                            \
          AF[ks], BF[nf][ks], acc[MB][(NB) + nf], 0, 0, 0);                                    \
  __builtin_amdgcn_s_setprio(0);

  f32x4 acc[2][4];
  #pragma unroll
  for (int i = 0; i < 2; ++i)
    #pragma unroll
    for (int j = 0; j < 4; ++j) acc[i][j] = (f32x4){0.f, 0.f, 0.f, 0.f};

  // bias prefetch (out of epilogue critical path)
  float bv[4];
  #pragma unroll
  for (int nf = 0; nf < 4; ++nf) bv[nf] = bias[tile_n + wn + nf * 16 + lr];

  bf16x8 a1[2], a2[2], b1[2][2], b2[2][2];

  // prologue: kt0 (buf0) fully + kt1 A (buf1); VMCNT2 retires exactly buf0's 4
  // loads BEFORE the barrier that releases readers (A-buf1 pair stays in flight).
  STAGE_A(0, 0, 0) STAGE_A(0, 0, 1) STAGE_B(0, 0, 0) STAGE_B(0, 0, 1)
  STAGE_A(1, 64, 0) STAGE_A(1, 64, 1)
  VMCNT2; BARRIER;

  // FIFO at p3-end: [A1odd,A1odd,B1odd,B1odd,A0k2,A0k2] -> VMCNT2 retires buf1's 4.
  // FIFO at p7-end: [A0k2,A0k2,B0k2,B0k2,A1k3,A1k3]     -> VMCNT2 retires buf0's 4.
#define ITER(I_, FULL)                                                                         \
  {                                                                                            \
    int k1 = (2*(I_)+1)*64, k2 = (2*(I_)+2)*64, k3 = (2*(I_)+3)*64;                            \
    /* p0: buf0 reads (all waves' buf0 DMA certified before the opening barrier) */            \
    READ_A1(a1, 0) READ_A2(a2, 0) READ_B(b1, 0, 0)                                             \
    STAGE_B(1, k1, 0) BARRIER; LGKMCNT0;                                                       \
    Q_MFMA(a1, b1, 0, 0) BARRIER;                                                              \
    /* p1 */                                                                                   \
    READ_B(b2, 32, 0) STAGE_B(1, k1, 1) BARRIER; LGKMCNT0;                                     \
    Q_MFMA(a1, b2, 0, 2) BARRIER;                                                              \
    /* p2 */                                                                                   \
    if (FULL) { STAGE_A(0, k2, 0) } BARRIER;                                                   \
    Q_MFMA(a2, b2, 1, 2) BARRIER;                                                              \
    /* p3: certify buf1 DMA before the barrier that opens p4 */                                \
    if (FULL) { STAGE_A(0, k2, 1) } BARRIER;                                                   \
    Q_MFMA(a2, b1, 1, 0)                                                                       \
    if (FULL) { VMCNT2; } else { VMCNT0; }                                                     \
    BARRIER;                                                                                   \
    /* p4: buf1 reads */                                                                       \
    READ_A1(a1, 1) READ_A2(a2, 1) READ_B(b1, 0, 1)                                             \
    if (FULL) { STAGE_B(0, k2, 0) } BARRIER; LGKMCNT0;                                         \
    Q_MFMA(a1, b1, 0, 0) BARRIER;                                                              \
    /* p5 */                                                                                   \
    READ_B(b2, 32, 1) if (FULL) { STAGE_B(0, k2, 1) } BARRIER; LGKMCNT0;                       \
    Q_MFMA(a1, b2, 0, 2) BARRIER;                                                              \
    /* p6 */                                                                                   \
    if (FULL) { STAGE_A(1, k3, 0) } BARRIER;                                                   \
    Q_MFMA(a2, b2, 1, 2) BARRIER;                                                              \
    /* p7: certify next-iter buf0 DMA before closing barrier */                                \
    if (FULL) { STAGE_A(1, k3, 1) } BARRIER;                                                   \
    Q_MFMA(a2, b1, 1, 0)                                                                       \
    if (FULL) { VMCNT2; }                                                                      \
    BARRIER;                                                                                   \
  }

  for (int I = 0; I < 7; ++I) ITER(I, 1)
  ITER(7, 0)
#undef ITER

  // epilogue: lane holds D[m=kg*4+r][o=lr] per 16x16 frag
  #pragma unroll
  for (int mf = 0; mf < 2; ++mf)
    #pragma unroll
    for (int nf = 0; nf < 4; ++nf) {
      int m = tile_m + wm + mf * 16 + kg * 4;
      int o = tile_n + wn + nf * 16 + lr;
      f32x4 v = acc[mf][nf];
      v[0] += bv[nf]; v[1] += bv[nf]; v[2] += bv[nf]; v[3] += bv[nf];
      *(f32x4*)&out[(size_t)(m >> 10) * 524288 + (size_t)o * 1024 + (size_t)(m & 1023)] = v;
    }
}

extern "C" void kernel_launch(void* const* d_in, const int* in_sizes, int n_in,
                              void* d_out, int out_size, void* d_ws, size_t ws_size,
                              hipStream_t stream) {
  (void)in_sizes; (void)n_in; (void)out_size; (void)ws_size;
  const float* in   = (const float*)d_in[0];
  const float* sf   = (const float*)d_in[1];
  const float* f0   = (const float*)d_in[2];
  const float* f1   = (const float*)d_in[3];
  const float* lf   = (const float*)d_in[4];
  const float* bias = (const float*)d_in[5];
  float* out = (float*)d_out;

  char* ws = (char*)d_ws;
  ushort_t* t      = (ushort_t*)ws;                          // 64 MB
  ushort_t* chainT = (ushort_t*)(ws + 67108864);             // 1 MB
  float*    g      = (float*)(ws + 67108864 + 1048576);      // 128 KB

  hipLaunchKernelGGL(chain_g_kernel, dim3(128),  dim3(256), 0, stream, f1, lf, g);
  hipLaunchKernelGGL(chain_kernel,   dim3(2048), dim3(256), 0, stream, f0, g, chainT);
  hipLaunchKernelGGL(conv_kernel,    dim3(1024), dim3(256), 0, stream, in, sf, t);
  hipLaunchKernelGGL(gemm_kernel,    dim3(1024), dim3(512), 0, stream, t, chainT, bias, out);
}